// Round 10
// baseline (216.187 us; speedup 1.0000x reference)
//
#include <hip/hip_runtime.h>
#include <hip/hip_fp16.h>
#include <cstdint>
#include <cstddef>

#define NB 4
#define NL 5
#define NC 256
#define NH 96
#define NW 192
#define NHW (NH * NW)
#define NPIX (NB * NHW)   // 73728
#define THRE 0.01f

typedef float __attribute__((ext_vector_type(4))) f32x4;

// ---------------- conf+mask fused: sigmoid/max -> 5x5 gauss -> threshold ----
#define TW 32
#define TH 8
__global__ __launch_bounds__(256) void mask_conv_kernel(const float* __restrict__ rm,
                                                        const float* __restrict__ g,
                                                        float* __restrict__ mask,
                                                        float* __restrict__ counter) {
    const int tilesX = NW / TW;               // 6
    const int tilesY = NH / TH;               // 12
    const int img = blockIdx.x / (tilesX * tilesY);
    const int tidx = blockIdx.x % (tilesX * tilesY);
    const int tx0 = (tidx % tilesX) * TW;
    const int ty0 = (tidx / tilesX) * TH;
    const int t = threadIdx.x;

    __shared__ float cs[TH + 4][TW + 4];

    for (int idx = t; idx < (TH + 4) * (TW + 4); idx += 256) {
        int ly = idx / (TW + 4), lx = idx % (TW + 4);
        int gy = ty0 + ly - 2, gx = tx0 + lx - 2;
        float v = 0.0f;
        if (gy >= 0 && gy < NH && gx >= 0 && gx < NW) {
            float a = rm[((size_t)img * 2 + 0) * NHW + gy * NW + gx];
            float b = rm[((size_t)img * 2 + 1) * NHW + gy * NW + gx];
            v = fmaxf(1.0f / (1.0f + expf(-a)), 1.0f / (1.0f + expf(-b)));
        }
        cs[ly][lx] = v;
    }
    __syncthreads();

    const int lx = t & 31, ly = t >> 5;
    float s = 0.0f;
#pragma unroll
    for (int ky = 0; ky < 5; ky++)
#pragma unroll
        for (int kx = 0; kx < 5; kx++)
            s += cs[ly + ky][lx + kx] * g[ky * 5 + kx];

    float mval = (s > THRE) ? 1.0f : 0.0f;
    mask[(size_t)img * NHW + (ty0 + ly) * NW + tx0 + lx] = mval;

    float cnt = (img % NL == 0) ? mval : 0.0f;
#pragma unroll
    for (int off = 32; off; off >>= 1) cnt += __shfl_down(cnt, off, 64);
    if ((t & 63) == 0 && cnt != 0.0f) atomicAdd(counter, cnt);
}

// ---------------- transpose: x[bm,c,p] fp32 -> xt[bm,p,c] half, mask folded ----
#define WPAD 129
__global__ __launch_bounds__(256) void transpose_kernel(const float* __restrict__ x,
                                                        const float* __restrict__ mask,
                                                        __half* __restrict__ xt) {
    const int bm = blockIdx.x / (NHW / 32);
    const int p0 = (blockIdx.x % (NHW / 32)) * 32;
    const int m = bm % NL;
    const int t = threadIdx.x;

    __shared__ unsigned int tile[32 * WPAD];   // 16.5 KB

    const int u = t & 7;        // pixel-quad index (4 px each)
    const int cp = t >> 3;      // channel-pair index 0..31

    float mv[4];
    if (m == 0) {
        mv[0] = mv[1] = mv[2] = mv[3] = 1.0f;
    } else {
#pragma unroll
        for (int j = 0; j < 4; j++)
            mv[j] = mask[(size_t)bm * NHW + p0 + u * 4 + j];
    }

#pragma unroll
    for (int k = 0; k < 4; k++) {
        const int c = cp * 2 + 64 * k;
        f32x4 f0 = __builtin_nontemporal_load(reinterpret_cast<const f32x4*>(
            x + ((size_t)bm * NC + c) * NHW + p0 + u * 4));
        f32x4 f1 = __builtin_nontemporal_load(reinterpret_cast<const f32x4*>(
            x + ((size_t)bm * NC + c + 1) * NHW + p0 + u * 4));
#pragma unroll
        for (int j = 0; j < 4; j++) {
            __half2 h = __halves2half2(__float2half(f0[j] * mv[j]),
                                       __float2half(f1[j] * mv[j]));
            tile[(u * 4 + j) * WPAD + cp + 32 * k] = *reinterpret_cast<unsigned int*>(&h);
        }
    }
    __syncthreads();

    const int uu = t & 31;      // 32 channel-octets
    const int pw = t >> 5;      // 0..7
#pragma unroll
    for (int j2 = 0; j2 < 4; j2++) {
        const int pl = pw + j2 * 8;
        const unsigned int* src = tile + pl * WPAD + uu * 4;
        uint4 val = make_uint4(src[0], src[1], src[2], src[3]);
        *reinterpret_cast<uint4*>(xt + ((size_t)bm * NHW + p0 + pl) * NC + uu * 8) = val;
    }
}

// ---------------- fused v4: m-granular rolling prefetch ----------------
// block: 32 consecutive pixels (one image row), 256 thr = 4 waves x 8 px.
// lane owns 4 channels. grid = NB * 576 (XCD-swizzled).
// Pipeline step = (pixel j, image m), cnt = 5j+m; buffers alternate by cnt&1
// (5 odd -> clean across pixels). Live: raw[2][4]+wtb[2][4]+v[5][4] ~ 100 VGPR
// -> 4 waves/SIMD, 4-8 loads in flight per wave.
__global__ __launch_bounds__(256) void fused_kernel(const __half* __restrict__ xt,
                                                    const float* __restrict__ M,
                                                    float* __restrict__ out) {
    const int tid = threadIdx.x, wid = tid >> 6, lane = tid & 63;
    const int nblk = NB * (NHW / 32);          // 2304, divisible by 8
    const int bid = (int)((blockIdx.x & 7) * (nblk / 8) + (blockIdx.x >> 3));
    const int b = bid / (NHW / 32);
    const int p0 = (bid % (NHW / 32)) * 32;

    __shared__ float otile[NC][33];
    __shared__ float sh_th[NL][6];

    if (tid < NL) {
        const int m = tid;
        const float* Mb = M + ((size_t)(b * NL) * NL + m) * 16;
        sh_th[m][0] = Mb[0];
        sh_th[m][1] = Mb[1] * ((float)NH / (float)NW);
        sh_th[m][2] = Mb[3] * (2.0f / (0.4f * (float)NW));
        sh_th[m][3] = Mb[4] * ((float)NW / (float)NH);
        sh_th[m][4] = Mb[5];
        sh_th[m][5] = Mb[7] * (2.0f / (0.4f * (float)NH));
    }
    __syncthreads();

    const int h = p0 / NW;
    const int w0 = p0 - h * NW;
    const float gy = (h + 0.5f) * (2.0f / NH) - 1.0f;

    float wtb[2][4];
    uint2 raw[2][4];

    // taps + 4-load issue for (pixel slot jj, image mm) into buffer bk
    auto issue = [&](int jj, int mm, int bk) {
        const int pl = wid * 8 + jj;
        const float gx = (w0 + pl + 0.5f) * (2.0f / NW) - 1.0f;
        float pxn = sh_th[mm][0] * gx + sh_th[mm][1] * gy + sh_th[mm][2];
        float pyn = sh_th[mm][3] * gx + sh_th[mm][4] * gy + sh_th[mm][5];
        float sx = ((pxn + 1.0f) * (float)NW - 1.0f) * 0.5f;
        float sy = ((pyn + 1.0f) * (float)NH - 1.0f) * 0.5f;
        float x0 = floorf(sx), y0 = floorf(sy);
        float fx = sx - x0, fy = sy - y0;
        const __half* base = xt + (size_t)(b * NL + mm) * NHW * NC + lane * 4;
#pragma unroll
        for (int ty = 0; ty < 2; ty++) {
#pragma unroll
            for (int tx = 0; tx < 2; tx++) {
                int tt = ty * 2 + tx;
                float xf = x0 + (float)tx, yf = y0 + (float)ty;
                bool valid = (xf >= 0.0f) && (xf <= (float)(NW - 1)) &&
                             (yf >= 0.0f) && (yf <= (float)(NH - 1));
                int ix = (int)fminf(fmaxf(xf, 0.0f), (float)(NW - 1));
                int iy = (int)fminf(fmaxf(yf, 0.0f), (float)(NH - 1));
                float wx = tx ? fx : (1.0f - fx);
                float wy = ty ? fy : (1.0f - fy);
                wtb[bk][tt] = wx * wy * (valid ? 1.0f : 0.0f);
                raw[bk][tt] = *reinterpret_cast<const uint2*>(
                    base + (iy * NW + ix) * NC);
            }
        }
    };

    issue(0, 0, 0);

#pragma unroll
    for (int j = 0; j < 8; j++) {
        const int pl = wid * 8 + j;

        float v[NL][4];
        float dt[NL];

#pragma unroll
        for (int m = 0; m < NL; m++) {
            const int cnt = j * 5 + m;
            const int bk = cnt & 1;
            // issue next step's 4 loads before consuming this one's
            if (cnt + 1 < 40) issue((cnt + 1) / 5, (cnt + 1) % 5, (cnt + 1) & 1);

            float acc0 = 0.f, acc1 = 0.f, acc2 = 0.f, acc3 = 0.f;
#pragma unroll
            for (int tt = 0; tt < 4; tt++) {
                const __half2* h2 = reinterpret_cast<const __half2*>(&raw[bk][tt]);
                float2 f01 = __half22float2(h2[0]);
                float2 f23 = __half22float2(h2[1]);
                float wv = wtb[bk][tt];
                acc0 += wv * f01.x;
                acc1 += wv * f01.y;
                acc2 += wv * f23.x;
                acc3 += wv * f23.y;
            }
            v[m][0] = acc0; v[m][1] = acc1; v[m][2] = acc2; v[m][3] = acc3;
            dt[m] = v[0][0] * acc0 + v[0][1] * acc1 + v[0][2] * acc2 + v[0][3] * acc3;
        }

#pragma unroll
        for (int m = 0; m < NL; m++) {
#pragma unroll
            for (int msk = 1; msk < 64; msk <<= 1)
                dt[m] += __shfl_xor(dt[m], msk, 64);
        }

        float mx = dt[0] * (1.0f / 16.0f);
#pragma unroll
        for (int m = 1; m < NL; m++) mx = fmaxf(mx, dt[m] * (1.0f / 16.0f));
        float pw[NL], sum = 0.0f;
#pragma unroll
        for (int m = 0; m < NL; m++) {
            pw[m] = __expf(dt[m] * (1.0f / 16.0f) - mx);
            sum += pw[m];
        }
        float inv = 1.0f / sum;

#pragma unroll
        for (int jj = 0; jj < 4; jj++) {
            float o = 0.0f;
#pragma unroll
            for (int m = 0; m < NL; m++) o += pw[m] * v[m][jj];
            otile[lane * 4 + jj][pl] = o * inv;
        }
    }
    __syncthreads();

    const int u = tid & 7;
#pragma unroll
    for (int k = 0; k < 8; k++) {
        const int c = (tid >> 3) + k * 32;
        float4 val = make_float4(otile[c][u * 4 + 0], otile[c][u * 4 + 1],
                                 otile[c][u * 4 + 2], otile[c][u * 4 + 3]);
        *reinterpret_cast<float4*>(out + ((size_t)b * NC + c) * NHW + p0 + u * 4) = val;
    }
}

// ---------------- finalize comm_rate ----------------
__global__ void finalize_kernel(const float* __restrict__ counter, float* __restrict__ out) {
    out[(size_t)NB * NC * NHW] = *counter / (float)(NB * NHW);
}

extern "C" void kernel_launch(void* const* d_in, const int* in_sizes, int n_in,
                              void* d_out, int out_size, void* d_ws, size_t ws_size,
                              hipStream_t stream) {
    const float* x  = (const float*)d_in[0];
    const float* rm = (const float*)d_in[1];
    const float* M  = (const float*)d_in[2];
    const float* g  = (const float*)d_in[3];
    float* out = (float*)d_out;

    float* counter = (float*)d_ws;                        // 16 floats (pad)
    float* mask    = counter + 16;                        // NB*NL*NHW floats
    __half* xt     = (__half*)(mask + (size_t)NB * NL * NHW); // 20*NHW*NC halves

    hipMemsetAsync(counter, 0, sizeof(float), stream);

    mask_conv_kernel<<<NB * NL * (NH / TH) * (NW / TW), 256, 0, stream>>>(rm, g, mask, counter);
    transpose_kernel<<<NB * NL * (NHW / 32), 256, 0, stream>>>(x, mask, xt);
    fused_kernel<<<NB * (NHW / 32), 256, 0, stream>>>(xt, M, out);
    finalize_kernel<<<1, 1, 0, stream>>>(counter, out);
}

// Round 11
// 182.624 us; speedup vs baseline: 1.1838x; 1.1838x over previous
//
#include <hip/hip_runtime.h>
#include <hip/hip_fp16.h>
#include <cstdint>
#include <cstddef>

#define NB 4
#define NL 5
#define NC 256
#define NH 96
#define NW 192
#define NHW (NH * NW)
#define NPIX (NB * NHW)   // 73728
#define THRE 0.01f

typedef float __attribute__((ext_vector_type(4))) f32x4;

// ---------------- conf+mask fused: sigmoid/max -> 5x5 gauss -> threshold ----
#define TW 32
#define TH 8
__global__ __launch_bounds__(256) void mask_conv_kernel(const float* __restrict__ rm,
                                                        const float* __restrict__ g,
                                                        float* __restrict__ mask,
                                                        float* __restrict__ counter) {
    const int tilesX = NW / TW;               // 6
    const int tilesY = NH / TH;               // 12
    const int img = blockIdx.x / (tilesX * tilesY);
    const int tidx = blockIdx.x % (tilesX * tilesY);
    const int tx0 = (tidx % tilesX) * TW;
    const int ty0 = (tidx / tilesX) * TH;
    const int t = threadIdx.x;

    __shared__ float cs[TH + 4][TW + 4];

    for (int idx = t; idx < (TH + 4) * (TW + 4); idx += 256) {
        int ly = idx / (TW + 4), lx = idx % (TW + 4);
        int gy = ty0 + ly - 2, gx = tx0 + lx - 2;
        float v = 0.0f;
        if (gy >= 0 && gy < NH && gx >= 0 && gx < NW) {
            float a = rm[((size_t)img * 2 + 0) * NHW + gy * NW + gx];
            float b = rm[((size_t)img * 2 + 1) * NHW + gy * NW + gx];
            v = fmaxf(1.0f / (1.0f + expf(-a)), 1.0f / (1.0f + expf(-b)));
        }
        cs[ly][lx] = v;
    }
    __syncthreads();

    const int lx = t & 31, ly = t >> 5;
    float s = 0.0f;
#pragma unroll
    for (int ky = 0; ky < 5; ky++)
#pragma unroll
        for (int kx = 0; kx < 5; kx++)
            s += cs[ly + ky][lx + kx] * g[ky * 5 + kx];

    float mval = (s > THRE) ? 1.0f : 0.0f;
    mask[(size_t)img * NHW + (ty0 + ly) * NW + tx0 + lx] = mval;

    float cnt = (img % NL == 0) ? mval : 0.0f;
#pragma unroll
    for (int off = 32; off; off >>= 1) cnt += __shfl_down(cnt, off, 64);
    if ((t & 63) == 0 && cnt != 0.0f) atomicAdd(counter, cnt);
}

// ---------------- transpose: x[bm,c,p] fp32 -> xt[bm,p,c] half, mask folded ----
#define WPAD 129
__global__ __launch_bounds__(256) void transpose_kernel(const float* __restrict__ x,
                                                        const float* __restrict__ mask,
                                                        __half* __restrict__ xt) {
    const int bm = blockIdx.x / (NHW / 32);
    const int p0 = (blockIdx.x % (NHW / 32)) * 32;
    const int m = bm % NL;
    const int t = threadIdx.x;

    __shared__ unsigned int tile[32 * WPAD];   // 16.5 KB

    const int u = t & 7;        // pixel-quad index (4 px each)
    const int cp = t >> 3;      // channel-pair index 0..31

    float mv[4];
    if (m == 0) {
        mv[0] = mv[1] = mv[2] = mv[3] = 1.0f;
    } else {
#pragma unroll
        for (int j = 0; j < 4; j++)
            mv[j] = mask[(size_t)bm * NHW + p0 + u * 4 + j];
    }

#pragma unroll
    for (int k = 0; k < 4; k++) {
        const int c = cp * 2 + 64 * k;
        f32x4 f0 = __builtin_nontemporal_load(reinterpret_cast<const f32x4*>(
            x + ((size_t)bm * NC + c) * NHW + p0 + u * 4));
        f32x4 f1 = __builtin_nontemporal_load(reinterpret_cast<const f32x4*>(
            x + ((size_t)bm * NC + c + 1) * NHW + p0 + u * 4));
#pragma unroll
        for (int j = 0; j < 4; j++) {
            __half2 h = __halves2half2(__float2half(f0[j] * mv[j]),
                                       __float2half(f1[j] * mv[j]));
            tile[(u * 4 + j) * WPAD + cp + 32 * k] = *reinterpret_cast<unsigned int*>(&h);
        }
    }
    __syncthreads();

    const int uu = t & 31;      // 32 channel-octets
    const int pw = t >> 5;      // 0..7
#pragma unroll
    for (int j2 = 0; j2 < 4; j2++) {
        const int pl = pw + j2 * 8;
        const unsigned int* src = tile + pl * WPAD + uu * 4;
        uint4 val = make_uint4(src[0], src[1], src[2], src[3]);
        *reinterpret_cast<uint4*>(xt + ((size_t)bm * NHW + p0 + pl) * NC + uu * 8) = val;
    }
}

// ---------------- fused v5: 32 lanes/pixel, 8 ch/lane, 2 px/wave ----------------
// block: 32 consecutive pixels (one image row), 256 thr = 4 waves.
// Each wave: 4 j-iters x 2 pixels (half-wave per pixel). lane&31 owns 8 ch.
// Butterfly: 5 levels within 32-lane halves (vs 6x64 before). Loads: uint4.
// Rolling (pixel-pair, m) prefetch, compile-time buffer indices.
__global__ __launch_bounds__(256) void fused_kernel(const __half* __restrict__ xt,
                                                    const float* __restrict__ M,
                                                    float* __restrict__ out) {
    const int tid = threadIdx.x, wid = tid >> 6, lane = tid & 63;
    const int half = lane >> 5, cl = lane & 31;
    const int nblk = NB * (NHW / 32);          // 2304, divisible by 8
    const int bid = (int)((blockIdx.x & 7) * (nblk / 8) + (blockIdx.x >> 3));
    const int b = bid / (NHW / 32);
    const int p0 = (bid % (NHW / 32)) * 32;

    __shared__ float otile[32][260];           // [px][c], pad 4 words
    __shared__ float sh_th[NL][6];

    if (tid < NL) {
        const int m = tid;
        const float* Mb = M + ((size_t)(b * NL) * NL + m) * 16;
        sh_th[m][0] = Mb[0];
        sh_th[m][1] = Mb[1] * ((float)NH / (float)NW);
        sh_th[m][2] = Mb[3] * (2.0f / (0.4f * (float)NW));
        sh_th[m][3] = Mb[4] * ((float)NW / (float)NH);
        sh_th[m][4] = Mb[5];
        sh_th[m][5] = Mb[7] * (2.0f / (0.4f * (float)NH));
    }
    __syncthreads();

    const int h = p0 / NW;
    const int w0 = p0 - h * NW;
    const float gy = (h + 0.5f) * (2.0f / NH) - 1.0f;

    float wtb[2][4];
    uint4 raw[2][4];

    // taps + 4 uint4 loads for (pixel-pair jj, image mm) into buffer bk.
    // Each half-wave handles its own pixel pl = wid*8 + jj*2 + half.
    auto issue = [&](int jj, int mm, int bk) {
        const int pl = wid * 8 + jj * 2 + half;
        const float gx = (w0 + pl + 0.5f) * (2.0f / NW) - 1.0f;
        float pxn = sh_th[mm][0] * gx + sh_th[mm][1] * gy + sh_th[mm][2];
        float pyn = sh_th[mm][3] * gx + sh_th[mm][4] * gy + sh_th[mm][5];
        float sx = ((pxn + 1.0f) * (float)NW - 1.0f) * 0.5f;
        float sy = ((pyn + 1.0f) * (float)NH - 1.0f) * 0.5f;
        float x0 = floorf(sx), y0 = floorf(sy);
        float fx = sx - x0, fy = sy - y0;
        const __half* base = xt + (size_t)(b * NL + mm) * NHW * NC + cl * 8;
#pragma unroll
        for (int ty = 0; ty < 2; ty++) {
#pragma unroll
            for (int tx = 0; tx < 2; tx++) {
                int tt = ty * 2 + tx;
                float xf = x0 + (float)tx, yf = y0 + (float)ty;
                bool valid = (xf >= 0.0f) && (xf <= (float)(NW - 1)) &&
                             (yf >= 0.0f) && (yf <= (float)(NH - 1));
                int ix = (int)fminf(fmaxf(xf, 0.0f), (float)(NW - 1));
                int iy = (int)fminf(fmaxf(yf, 0.0f), (float)(NH - 1));
                float wx = tx ? fx : (1.0f - fx);
                float wy = ty ? fy : (1.0f - fy);
                wtb[bk][tt] = wx * wy * (valid ? 1.0f : 0.0f);
                raw[bk][tt] = *reinterpret_cast<const uint4*>(
                    base + (size_t)(iy * NW + ix) * NC);
            }
        }
    };

    issue(0, 0, 0);

#pragma unroll
    for (int j = 0; j < 4; j++) {
        const int pl = wid * 8 + j * 2 + half;

        float v[NL][8];
        float dt[NL];

#pragma unroll
        for (int m = 0; m < NL; m++) {
            const int cnt = j * 5 + m;
            const int bk = cnt & 1;
            if (cnt + 1 < 20) issue((cnt + 1) / 5, (cnt + 1) % 5, (cnt + 1) & 1);

            float acc[8] = {0.f, 0.f, 0.f, 0.f, 0.f, 0.f, 0.f, 0.f};
#pragma unroll
            for (int tt = 0; tt < 4; tt++) {
                const __half2* h2 = reinterpret_cast<const __half2*>(&raw[bk][tt]);
                const float wv = wtb[bk][tt];
#pragma unroll
                for (int q = 0; q < 4; q++) {
                    float2 f = __half22float2(h2[q]);
                    acc[2 * q]     += wv * f.x;
                    acc[2 * q + 1] += wv * f.y;
                }
            }
            float d = 0.f;
#pragma unroll
            for (int k = 0; k < 8; k++) { v[m][k] = acc[k]; d += v[0][k] * acc[k]; }
            dt[m] = d;
        }

        // 5-level butterfly within each 32-lane half (full 256-ch dot)
#pragma unroll
        for (int m = 0; m < NL; m++) {
#pragma unroll
            for (int msk = 1; msk < 32; msk <<= 1)
                dt[m] += __shfl_xor(dt[m], msk, 64);
        }

        float mx = dt[0] * (1.0f / 16.0f);
#pragma unroll
        for (int m = 1; m < NL; m++) mx = fmaxf(mx, dt[m] * (1.0f / 16.0f));
        float pw[NL], sum = 0.0f;
#pragma unroll
        for (int m = 0; m < NL; m++) {
            pw[m] = __expf(dt[m] * (1.0f / 16.0f) - mx);
            sum += pw[m];
        }
        float inv = 1.0f / sum;

#pragma unroll
        for (int k = 0; k < 8; k++) {
            float o = 0.0f;
#pragma unroll
            for (int m = 0; m < NL; m++) o += pw[m] * v[m][k];
            otile[pl][cl * 8 + k] = o * inv;
        }
    }
    __syncthreads();

    const int u = tid & 7;
#pragma unroll
    for (int k = 0; k < 8; k++) {
        const int c = (tid >> 3) + k * 32;
        float4 val = make_float4(otile[u * 4 + 0][c], otile[u * 4 + 1][c],
                                 otile[u * 4 + 2][c], otile[u * 4 + 3][c]);
        *reinterpret_cast<float4*>(out + ((size_t)b * NC + c) * NHW + p0 + u * 4) = val;
    }
}

// ---------------- finalize comm_rate ----------------
__global__ void finalize_kernel(const float* __restrict__ counter, float* __restrict__ out) {
    out[(size_t)NB * NC * NHW] = *counter / (float)(NB * NHW);
}

extern "C" void kernel_launch(void* const* d_in, const int* in_sizes, int n_in,
                              void* d_out, int out_size, void* d_ws, size_t ws_size,
                              hipStream_t stream) {
    const float* x  = (const float*)d_in[0];
    const float* rm = (const float*)d_in[1];
    const float* M  = (const float*)d_in[2];
    const float* g  = (const float*)d_in[3];
    float* out = (float*)d_out;

    float* counter = (float*)d_ws;                        // 16 floats (pad)
    float* mask    = counter + 16;                        // NB*NL*NHW floats
    __half* xt     = (__half*)(mask + (size_t)NB * NL * NHW); // 20*NHW*NC halves

    hipMemsetAsync(counter, 0, sizeof(float), stream);

    mask_conv_kernel<<<NB * NL * (NH / TH) * (NW / TW), 256, 0, stream>>>(rm, g, mask, counter);
    transpose_kernel<<<NB * NL * (NHW / 32), 256, 0, stream>>>(x, mask, xt);
    fused_kernel<<<NB * (NHW / 32), 256, 0, stream>>>(xt, M, out);
    finalize_kernel<<<1, 1, 0, stream>>>(counter, out);
}

// Round 12
// 172.561 us; speedup vs baseline: 1.2528x; 1.0583x over previous
//
#include <hip/hip_runtime.h>
#include <hip/hip_fp16.h>
#include <cstdint>
#include <cstddef>

#define NB 4
#define NL 5
#define NC 256
#define NH 96
#define NW 192
#define NHW (NH * NW)
#define NPIX (NB * NHW)   // 73728
#define THRE 0.01f

typedef float __attribute__((ext_vector_type(4))) f32x4;

// ---------------- transpose v3: x[bm,c,p] fp32 -> xt[bm,p,c] half ------------
// Inline mask: 5x36 conf neighborhood -> 5x5 gauss -> threshold (mask_conv
// kernel eliminated). All 8 x-loads issued before any consumption (MLP=8),
// in flight under the mask phase. bm%5==0 blocks accumulate comm counter.
#define WPAD 129
__global__ __launch_bounds__(256) void transpose_kernel(const float* __restrict__ x,
                                                        const float* __restrict__ rm,
                                                        const float* __restrict__ g,
                                                        __half* __restrict__ xt,
                                                        float* __restrict__ counter) {
    const int bm = blockIdx.x / (NHW / 32);
    const int p0 = (blockIdx.x % (NHW / 32)) * 32;
    const int m = bm % NL;
    const int bimg = bm / NL;
    const int t = threadIdx.x;

    __shared__ unsigned int tile[32 * WPAD];   // 16.5 KB
    __shared__ float cs[5][36];
    __shared__ float smask[32];

    const int u = t & 7;        // pixel-quad index (4 px each)
    const int cp = t >> 3;      // channel-pair index 0..31

    // ---- issue all 8 global loads up front (stay in flight) ----
    f32x4 f[8];
#pragma unroll
    for (int k = 0; k < 4; k++) {
        const int c = cp * 2 + 64 * k;
        f[2 * k] = __builtin_nontemporal_load(reinterpret_cast<const f32x4*>(
            x + ((size_t)bm * NC + c) * NHW + p0 + u * 4));
        f[2 * k + 1] = __builtin_nontemporal_load(reinterpret_cast<const f32x4*>(
            x + ((size_t)bm * NC + c + 1) * NHW + p0 + u * 4));
    }

    // ---- mask phase (overlaps with loads) ----
    const int h = p0 / NW;
    const int w0 = p0 - h * NW;
    if (t < 180) {
        const int ly = t / 36, lx = t - 36 * (t / 36);
        const int gy = h + ly - 2, gx = w0 + lx - 2;
        float v = 0.0f;
        if (gy >= 0 && gy < NH && gx >= 0 && gx < NW) {
            float a = rm[((size_t)bm * 2 + 0) * NHW + gy * NW + gx];
            float bb = rm[((size_t)bm * 2 + 1) * NHW + gy * NW + gx];
            v = fmaxf(1.0f / (1.0f + expf(-a)), 1.0f / (1.0f + expf(-bb)));
        }
        cs[ly][lx] = v;
    }
    __syncthreads();

    if (t < 32) {
        float s = 0.0f;
#pragma unroll
        for (int ky = 0; ky < 5; ky++)
#pragma unroll
            for (int kx = 0; kx < 5; kx++)
                s += cs[ky][t + kx] * g[ky * 5 + kx];
        smask[t] = (s > THRE) ? 1.0f : 0.0f;
    }
    __syncthreads();

    // comm counter: only image-0 blocks (bm%NL==0); lane-0 tree over lanes<32
    if (m == 0) {
        float cnt = (t < 32) ? smask[t] : 0.0f;
#pragma unroll
        for (int off = 16; off; off >>= 1) cnt += __shfl_down(cnt, off, 64);
        if (t == 0 && cnt != 0.0f) atomicAdd(counter, cnt);
    }

    float mv[4];
#pragma unroll
    for (int j = 0; j < 4; j++)
        mv[j] = (m == 0) ? 1.0f : smask[u * 4 + j];

    // ---- convert + LDS transpose ----
#pragma unroll
    for (int k = 0; k < 4; k++) {
#pragma unroll
        for (int j = 0; j < 4; j++) {
            __half2 hh = __halves2half2(__float2half(f[2 * k][j] * mv[j]),
                                        __float2half(f[2 * k + 1][j] * mv[j]));
            tile[(u * 4 + j) * WPAD + cp + 32 * k] = *reinterpret_cast<unsigned int*>(&hh);
        }
    }
    __syncthreads();

    const int uu = t & 31;      // 32 channel-octets
    const int pw = t >> 5;      // 0..7
#pragma unroll
    for (int j2 = 0; j2 < 4; j2++) {
        const int pl = pw + j2 * 8;
        const unsigned int* src = tile + pl * WPAD + uu * 4;
        uint4 val = make_uint4(src[0], src[1], src[2], src[3]);
        *reinterpret_cast<uint4*>(xt + ((size_t)bm * NHW + p0 + pl) * NC + uu * 8) = val;
    }
}

// ---------------- fused v5: 32 lanes/pixel, 8 ch/lane, 2 px/wave ----------------
// block: 32 consecutive pixels (one image row), 256 thr = 4 waves.
// Each wave: 4 j-iters x 2 pixels (half-wave per pixel). lane&31 owns 8 ch.
// Rolling (pixel-pair, m) prefetch, compile-time buffer indices.
__global__ __launch_bounds__(256) void fused_kernel(const __half* __restrict__ xt,
                                                    const float* __restrict__ M,
                                                    float* __restrict__ out) {
    const int tid = threadIdx.x, wid = tid >> 6, lane = tid & 63;
    const int half = lane >> 5, cl = lane & 31;
    const int nblk = NB * (NHW / 32);          // 2304, divisible by 8
    const int bid = (int)((blockIdx.x & 7) * (nblk / 8) + (blockIdx.x >> 3));
    const int b = bid / (NHW / 32);
    const int p0 = (bid % (NHW / 32)) * 32;

    __shared__ float otile[32][260];           // [px][c], pad 4 words
    __shared__ float sh_th[NL][6];

    if (tid < NL) {
        const int m = tid;
        const float* Mb = M + ((size_t)(b * NL) * NL + m) * 16;
        sh_th[m][0] = Mb[0];
        sh_th[m][1] = Mb[1] * ((float)NH / (float)NW);
        sh_th[m][2] = Mb[3] * (2.0f / (0.4f * (float)NW));
        sh_th[m][3] = Mb[4] * ((float)NW / (float)NH);
        sh_th[m][4] = Mb[5];
        sh_th[m][5] = Mb[7] * (2.0f / (0.4f * (float)NH));
    }
    __syncthreads();

    const int h = p0 / NW;
    const int w0 = p0 - h * NW;
    const float gy = (h + 0.5f) * (2.0f / NH) - 1.0f;

    float wtb[2][4];
    uint4 raw[2][4];

    auto issue = [&](int jj, int mm, int bk) {
        const int pl = wid * 8 + jj * 2 + half;
        const float gx = (w0 + pl + 0.5f) * (2.0f / NW) - 1.0f;
        float pxn = sh_th[mm][0] * gx + sh_th[mm][1] * gy + sh_th[mm][2];
        float pyn = sh_th[mm][3] * gx + sh_th[mm][4] * gy + sh_th[mm][5];
        float sx = ((pxn + 1.0f) * (float)NW - 1.0f) * 0.5f;
        float sy = ((pyn + 1.0f) * (float)NH - 1.0f) * 0.5f;
        float x0 = floorf(sx), y0 = floorf(sy);
        float fx = sx - x0, fy = sy - y0;
        const __half* base = xt + (size_t)(b * NL + mm) * NHW * NC + cl * 8;
#pragma unroll
        for (int ty = 0; ty < 2; ty++) {
#pragma unroll
            for (int tx = 0; tx < 2; tx++) {
                int tt = ty * 2 + tx;
                float xf = x0 + (float)tx, yf = y0 + (float)ty;
                bool valid = (xf >= 0.0f) && (xf <= (float)(NW - 1)) &&
                             (yf >= 0.0f) && (yf <= (float)(NH - 1));
                int ix = (int)fminf(fmaxf(xf, 0.0f), (float)(NW - 1));
                int iy = (int)fminf(fmaxf(yf, 0.0f), (float)(NH - 1));
                float wx = tx ? fx : (1.0f - fx);
                float wy = ty ? fy : (1.0f - fy);
                wtb[bk][tt] = wx * wy * (valid ? 1.0f : 0.0f);
                raw[bk][tt] = *reinterpret_cast<const uint4*>(
                    base + (size_t)(iy * NW + ix) * NC);
            }
        }
    };

    issue(0, 0, 0);

#pragma unroll
    for (int j = 0; j < 4; j++) {
        const int pl = wid * 8 + j * 2 + half;

        float v[NL][8];
        float dt[NL];

#pragma unroll
        for (int m = 0; m < NL; m++) {
            const int cnt = j * 5 + m;
            const int bk = cnt & 1;
            if (cnt + 1 < 20) issue((cnt + 1) / 5, (cnt + 1) % 5, (cnt + 1) & 1);

            float acc[8] = {0.f, 0.f, 0.f, 0.f, 0.f, 0.f, 0.f, 0.f};
#pragma unroll
            for (int tt = 0; tt < 4; tt++) {
                const __half2* h2 = reinterpret_cast<const __half2*>(&raw[bk][tt]);
                const float wv = wtb[bk][tt];
#pragma unroll
                for (int q = 0; q < 4; q++) {
                    float2 ff = __half22float2(h2[q]);
                    acc[2 * q]     += wv * ff.x;
                    acc[2 * q + 1] += wv * ff.y;
                }
            }
            float d = 0.f;
#pragma unroll
            for (int k = 0; k < 8; k++) { v[m][k] = acc[k]; d += v[0][k] * acc[k]; }
            dt[m] = d;
        }

#pragma unroll
        for (int m = 0; m < NL; m++) {
#pragma unroll
            for (int msk = 1; msk < 32; msk <<= 1)
                dt[m] += __shfl_xor(dt[m], msk, 64);
        }

        float mx = dt[0] * (1.0f / 16.0f);
#pragma unroll
        for (int m = 1; m < NL; m++) mx = fmaxf(mx, dt[m] * (1.0f / 16.0f));
        float pw[NL], sum = 0.0f;
#pragma unroll
        for (int m = 0; m < NL; m++) {
            pw[m] = __expf(dt[m] * (1.0f / 16.0f) - mx);
            sum += pw[m];
        }
        float inv = 1.0f / sum;

#pragma unroll
        for (int k = 0; k < 8; k++) {
            float o = 0.0f;
#pragma unroll
            for (int m = 0; m < NL; m++) o += pw[m] * v[m][k];
            otile[pl][cl * 8 + k] = o * inv;
        }
    }
    __syncthreads();

    const int u = tid & 7;
#pragma unroll
    for (int k = 0; k < 8; k++) {
        const int c = (tid >> 3) + k * 32;
        float4 val = make_float4(otile[u * 4 + 0][c], otile[u * 4 + 1][c],
                                 otile[u * 4 + 2][c], otile[u * 4 + 3][c]);
        *reinterpret_cast<float4*>(out + ((size_t)b * NC + c) * NHW + p0 + u * 4) = val;
    }
}

// ---------------- finalize comm_rate ----------------
__global__ void finalize_kernel(const float* __restrict__ counter, float* __restrict__ out) {
    out[(size_t)NB * NC * NHW] = *counter / (float)(NB * NHW);
}

extern "C" void kernel_launch(void* const* d_in, const int* in_sizes, int n_in,
                              void* d_out, int out_size, void* d_ws, size_t ws_size,
                              hipStream_t stream) {
    const float* x  = (const float*)d_in[0];
    const float* rm = (const float*)d_in[1];
    const float* M  = (const float*)d_in[2];
    const float* g  = (const float*)d_in[3];
    float* out = (float*)d_out;

    float* counter = (float*)d_ws;                        // 16 floats (pad)
    __half* xt     = (__half*)(counter + 16);             // 20*NHW*NC halves

    hipMemsetAsync(counter, 0, sizeof(float), stream);

    transpose_kernel<<<NB * NL * (NHW / 32), 256, 0, stream>>>(x, rm, g, xt, counter);
    fused_kernel<<<NB * (NHW / 32), 256, 0, stream>>>(xt, M, out);
    finalize_kernel<<<1, 1, 0, stream>>>(counter, out);
}

// Round 13
// 164.151 us; speedup vs baseline: 1.3170x; 1.0512x over previous
//
#include <hip/hip_runtime.h>
#include <hip/hip_fp16.h>
#include <cstdint>
#include <cstddef>

#define NB 4
#define NL 5
#define NC 256
#define NH 96
#define NW 192
#define NHW (NH * NW)
#define NPIX (NB * NHW)   // 73728
#define THRE 0.01f

typedef float __attribute__((ext_vector_type(4))) f32x4;

// ---------------- transpose v4: 64 px/block, double subtile -----------------
// x[bm,c,p] fp32 -> xt[bm,p,c] half, mask folded. Inline mask for the whole
// 64-px row (one 5x68 halo). 16 f32x4 loads issued up front; two 32-px
// LDS subtiles written after one barrier, stored after a second.
#define WPAD 129
__global__ __launch_bounds__(256) void transpose_kernel(const float* __restrict__ x,
                                                        const float* __restrict__ rm,
                                                        const float* __restrict__ g,
                                                        __half* __restrict__ xt,
                                                        float* __restrict__ counter) {
    const int bm = blockIdx.x / (NHW / 64);
    const int p0 = (blockIdx.x % (NHW / 64)) * 64;
    const int m = bm % NL;
    const int t = threadIdx.x;

    __shared__ unsigned int tileA[32 * WPAD];  // 16.5 KB
    __shared__ unsigned int tileB[32 * WPAD];  // 16.5 KB
    __shared__ float cs[5][68];
    __shared__ float smask[64];

    const int u = t & 7;        // pixel-quad within 32-px subtile
    const int cp = t >> 3;      // channel-pair index 0..31

    // ---- issue all 16 global loads up front (stay in flight) ----
    f32x4 fA[8], fB[8];
#pragma unroll
    for (int k = 0; k < 4; k++) {
        const int c = cp * 2 + 64 * k;
        const float* base0 = x + ((size_t)bm * NC + c) * NHW + p0 + u * 4;
        const float* base1 = x + ((size_t)bm * NC + c + 1) * NHW + p0 + u * 4;
        fA[2 * k]     = __builtin_nontemporal_load(reinterpret_cast<const f32x4*>(base0));
        fA[2 * k + 1] = __builtin_nontemporal_load(reinterpret_cast<const f32x4*>(base1));
        fB[2 * k]     = __builtin_nontemporal_load(reinterpret_cast<const f32x4*>(base0 + 32));
        fB[2 * k + 1] = __builtin_nontemporal_load(reinterpret_cast<const f32x4*>(base1 + 32));
    }

    // ---- mask phase for the full 64-px row (overlaps with loads) ----
    const int h = p0 / NW;
    const int w0 = p0 - h * NW;          // p0 multiple of 64, row-aligned
    if (t < 170) {
#pragma unroll
        for (int rr = 0; rr < 2; rr++) {
            const int idx = t + rr * 170;
            const int ly = idx / 68, lx = idx - 68 * (idx / 68);
            const int gy = h + ly - 2, gx = w0 + lx - 2;
            float v = 0.0f;
            if (gy >= 0 && gy < NH && gx >= 0 && gx < NW) {
                float a  = rm[((size_t)bm * 2 + 0) * NHW + gy * NW + gx];
                float bb = rm[((size_t)bm * 2 + 1) * NHW + gy * NW + gx];
                v = fmaxf(1.0f / (1.0f + expf(-a)), 1.0f / (1.0f + expf(-bb)));
            }
            cs[ly][lx] = v;
        }
    }
    __syncthreads();

    if (t < 64) {
        float s = 0.0f;
#pragma unroll
        for (int ky = 0; ky < 5; ky++)
#pragma unroll
            for (int kx = 0; kx < 5; kx++)
                s += cs[ky][t + kx] * g[ky * 5 + kx];
        smask[t] = (s > THRE) ? 1.0f : 0.0f;
    }
    __syncthreads();

    // comm counter: image-0 blocks only; wave 0 reduces the 64 mask values
    if (m == 0 && t < 64) {
        float cnt = smask[t];
#pragma unroll
        for (int off = 32; off; off >>= 1) cnt += __shfl_down(cnt, off, 64);
        if (t == 0 && cnt != 0.0f) atomicAdd(counter, cnt);
    }

    // ---- convert + LDS transpose (both subtiles) ----
#pragma unroll
    for (int k = 0; k < 4; k++) {
#pragma unroll
        for (int j = 0; j < 4; j++) {
            const float mA = (m == 0) ? 1.0f : smask[u * 4 + j];
            const float mB = (m == 0) ? 1.0f : smask[32 + u * 4 + j];
            __half2 hA = __halves2half2(__float2half(fA[2 * k][j] * mA),
                                        __float2half(fA[2 * k + 1][j] * mA));
            __half2 hB = __halves2half2(__float2half(fB[2 * k][j] * mB),
                                        __float2half(fB[2 * k + 1][j] * mB));
            tileA[(u * 4 + j) * WPAD + cp + 32 * k] = *reinterpret_cast<unsigned int*>(&hA);
            tileB[(u * 4 + j) * WPAD + cp + 32 * k] = *reinterpret_cast<unsigned int*>(&hB);
        }
    }
    __syncthreads();

    // ---- stores: 1 KB contiguous per wave per iter ----
    const int uu = t & 31;      // 32 channel-octets
    const int pw = t >> 5;      // 0..7
#pragma unroll
    for (int j2 = 0; j2 < 4; j2++) {
        const int pl = pw + j2 * 8;
        const unsigned int* srcA = tileA + pl * WPAD + uu * 4;
        const unsigned int* srcB = tileB + pl * WPAD + uu * 4;
        uint4 valA = make_uint4(srcA[0], srcA[1], srcA[2], srcA[3]);
        uint4 valB = make_uint4(srcB[0], srcB[1], srcB[2], srcB[3]);
        *reinterpret_cast<uint4*>(xt + ((size_t)bm * NHW + p0 + pl) * NC + uu * 8) = valA;
        *reinterpret_cast<uint4*>(xt + ((size_t)bm * NHW + p0 + 32 + pl) * NC + uu * 8) = valB;
    }
}

// ---------------- fused v5: 32 lanes/pixel, 8 ch/lane, 2 px/wave ----------------
__global__ __launch_bounds__(256) void fused_kernel(const __half* __restrict__ xt,
                                                    const float* __restrict__ M,
                                                    float* __restrict__ out) {
    const int tid = threadIdx.x, wid = tid >> 6, lane = tid & 63;
    const int half = lane >> 5, cl = lane & 31;
    const int nblk = NB * (NHW / 32);          // 2304, divisible by 8
    const int bid = (int)((blockIdx.x & 7) * (nblk / 8) + (blockIdx.x >> 3));
    const int b = bid / (NHW / 32);
    const int p0 = (bid % (NHW / 32)) * 32;

    __shared__ float otile[32][260];
    __shared__ float sh_th[NL][6];

    if (tid < NL) {
        const int m = tid;
        const float* Mb = M + ((size_t)(b * NL) * NL + m) * 16;
        sh_th[m][0] = Mb[0];
        sh_th[m][1] = Mb[1] * ((float)NH / (float)NW);
        sh_th[m][2] = Mb[3] * (2.0f / (0.4f * (float)NW));
        sh_th[m][3] = Mb[4] * ((float)NW / (float)NH);
        sh_th[m][4] = Mb[5];
        sh_th[m][5] = Mb[7] * (2.0f / (0.4f * (float)NH));
    }
    __syncthreads();

    const int h = p0 / NW;
    const int w0 = p0 - h * NW;
    const float gy = (h + 0.5f) * (2.0f / NH) - 1.0f;

    float wtb[2][4];
    uint4 raw[2][4];

    auto issue = [&](int jj, int mm, int bk) {
        const int pl = wid * 8 + jj * 2 + half;
        const float gx = (w0 + pl + 0.5f) * (2.0f / NW) - 1.0f;
        float pxn = sh_th[mm][0] * gx + sh_th[mm][1] * gy + sh_th[mm][2];
        float pyn = sh_th[mm][3] * gx + sh_th[mm][4] * gy + sh_th[mm][5];
        float sx = ((pxn + 1.0f) * (float)NW - 1.0f) * 0.5f;
        float sy = ((pyn + 1.0f) * (float)NH - 1.0f) * 0.5f;
        float x0 = floorf(sx), y0 = floorf(sy);
        float fx = sx - x0, fy = sy - y0;
        const __half* base = xt + (size_t)(b * NL + mm) * NHW * NC + cl * 8;
#pragma unroll
        for (int ty = 0; ty < 2; ty++) {
#pragma unroll
            for (int tx = 0; tx < 2; tx++) {
                int tt = ty * 2 + tx;
                float xf = x0 + (float)tx, yf = y0 + (float)ty;
                bool valid = (xf >= 0.0f) && (xf <= (float)(NW - 1)) &&
                             (yf >= 0.0f) && (yf <= (float)(NH - 1));
                int ix = (int)fminf(fmaxf(xf, 0.0f), (float)(NW - 1));
                int iy = (int)fminf(fmaxf(yf, 0.0f), (float)(NH - 1));
                float wx = tx ? fx : (1.0f - fx);
                float wy = ty ? fy : (1.0f - fy);
                wtb[bk][tt] = wx * wy * (valid ? 1.0f : 0.0f);
                raw[bk][tt] = *reinterpret_cast<const uint4*>(
                    base + (size_t)(iy * NW + ix) * NC);
            }
        }
    };

    issue(0, 0, 0);

#pragma unroll
    for (int j = 0; j < 4; j++) {
        const int pl = wid * 8 + j * 2 + half;

        float v[NL][8];
        float dt[NL];

#pragma unroll
        for (int m = 0; m < NL; m++) {
            const int cnt = j * 5 + m;
            const int bk = cnt & 1;
            if (cnt + 1 < 20) issue((cnt + 1) / 5, (cnt + 1) % 5, (cnt + 1) & 1);

            float acc[8] = {0.f, 0.f, 0.f, 0.f, 0.f, 0.f, 0.f, 0.f};
#pragma unroll
            for (int tt = 0; tt < 4; tt++) {
                const __half2* h2 = reinterpret_cast<const __half2*>(&raw[bk][tt]);
                const float wv = wtb[bk][tt];
#pragma unroll
                for (int q = 0; q < 4; q++) {
                    float2 ff = __half22float2(h2[q]);
                    acc[2 * q]     += wv * ff.x;
                    acc[2 * q + 1] += wv * ff.y;
                }
            }
            float d = 0.f;
#pragma unroll
            for (int k = 0; k < 8; k++) { v[m][k] = acc[k]; d += v[0][k] * acc[k]; }
            dt[m] = d;
        }

#pragma unroll
        for (int m = 0; m < NL; m++) {
#pragma unroll
            for (int msk = 1; msk < 32; msk <<= 1)
                dt[m] += __shfl_xor(dt[m], msk, 64);
        }

        float mx = dt[0] * (1.0f / 16.0f);
#pragma unroll
        for (int m = 1; m < NL; m++) mx = fmaxf(mx, dt[m] * (1.0f / 16.0f));
        float pw[NL], sum = 0.0f;
#pragma unroll
        for (int m = 0; m < NL; m++) {
            pw[m] = __expf(dt[m] * (1.0f / 16.0f) - mx);
            sum += pw[m];
        }
        float inv = 1.0f / sum;

#pragma unroll
        for (int k = 0; k < 8; k++) {
            float o = 0.0f;
#pragma unroll
            for (int m = 0; m < NL; m++) o += pw[m] * v[m][k];
            otile[pl][cl * 8 + k] = o * inv;
        }
    }
    __syncthreads();

    const int u = tid & 7;
#pragma unroll
    for (int k = 0; k < 8; k++) {
        const int c = (tid >> 3) + k * 32;
        float4 val = make_float4(otile[u * 4 + 0][c], otile[u * 4 + 1][c],
                                 otile[u * 4 + 2][c], otile[u * 4 + 3][c]);
        *reinterpret_cast<float4*>(out + ((size_t)b * NC + c) * NHW + p0 + u * 4) = val;
    }
}

// ---------------- finalize comm_rate ----------------
__global__ void finalize_kernel(const float* __restrict__ counter, float* __restrict__ out) {
    out[(size_t)NB * NC * NHW] = *counter / (float)(NB * NHW);
}

extern "C" void kernel_launch(void* const* d_in, const int* in_sizes, int n_in,
                              void* d_out, int out_size, void* d_ws, size_t ws_size,
                              hipStream_t stream) {
    const float* x  = (const float*)d_in[0];
    const float* rm = (const float*)d_in[1];
    const float* M  = (const float*)d_in[2];
    const float* g  = (const float*)d_in[3];
    float* out = (float*)d_out;

    float* counter = (float*)d_ws;                        // 16 floats (pad)
    __half* xt     = (__half*)(counter + 16);             // 20*NHW*NC halves

    hipMemsetAsync(counter, 0, sizeof(float), stream);

    transpose_kernel<<<NB * NL * (NHW / 64), 256, 0, stream>>>(x, rm, g, xt, counter);
    fused_kernel<<<NB * (NHW / 32), 256, 0, stream>>>(xt, M, out);
    finalize_kernel<<<1, 1, 0, stream>>>(counter, out);
}

// Round 14
// 161.220 us; speedup vs baseline: 1.3409x; 1.0182x over previous
//
#include <hip/hip_runtime.h>
#include <hip/hip_fp16.h>
#include <cstdint>
#include <cstddef>

#define NB 4
#define NL 5
#define NC 256
#define NH 96
#define NW 192
#define NHW (NH * NW)
#define NPIX (NB * NHW)   // 73728
#define THRE 0.01f

typedef float __attribute__((ext_vector_type(4))) f32x4;

// ---------------- transpose v4: 64 px/block, double subtile -----------------
// x[bm,c,p] fp32 -> xt[bm,p,c] half, mask folded. Inline mask for the whole
// 64-px row (one 5x68 halo). 16 f32x4 loads issued up front; two 32-px
// LDS subtiles. At 5.9 TB/s (94% of achievable) -- BW ceiling for this pattern.
#define WPAD 129
__global__ __launch_bounds__(256) void transpose_kernel(const float* __restrict__ x,
                                                        const float* __restrict__ rm,
                                                        const float* __restrict__ g,
                                                        __half* __restrict__ xt,
                                                        float* __restrict__ counter) {
    const int bm = blockIdx.x / (NHW / 64);
    const int p0 = (blockIdx.x % (NHW / 64)) * 64;
    const int m = bm % NL;
    const int t = threadIdx.x;

    __shared__ unsigned int tileA[32 * WPAD];  // 16.5 KB
    __shared__ unsigned int tileB[32 * WPAD];  // 16.5 KB
    __shared__ float cs[5][68];
    __shared__ float smask[64];

    const int u = t & 7;        // pixel-quad within 32-px subtile
    const int cp = t >> 3;      // channel-pair index 0..31

    // ---- issue all 16 global loads up front (stay in flight) ----
    f32x4 fA[8], fB[8];
#pragma unroll
    for (int k = 0; k < 4; k++) {
        const int c = cp * 2 + 64 * k;
        const float* base0 = x + ((size_t)bm * NC + c) * NHW + p0 + u * 4;
        const float* base1 = x + ((size_t)bm * NC + c + 1) * NHW + p0 + u * 4;
        fA[2 * k]     = __builtin_nontemporal_load(reinterpret_cast<const f32x4*>(base0));
        fA[2 * k + 1] = __builtin_nontemporal_load(reinterpret_cast<const f32x4*>(base1));
        fB[2 * k]     = __builtin_nontemporal_load(reinterpret_cast<const f32x4*>(base0 + 32));
        fB[2 * k + 1] = __builtin_nontemporal_load(reinterpret_cast<const f32x4*>(base1 + 32));
    }

    // ---- mask phase for the full 64-px row (overlaps with loads) ----
    const int h = p0 / NW;
    const int w0 = p0 - h * NW;          // p0 multiple of 64, row-aligned
    if (t < 170) {
#pragma unroll
        for (int rr = 0; rr < 2; rr++) {
            const int idx = t + rr * 170;
            const int ly = idx / 68, lx = idx - 68 * (idx / 68);
            const int gy = h + ly - 2, gx = w0 + lx - 2;
            float v = 0.0f;
            if (gy >= 0 && gy < NH && gx >= 0 && gx < NW) {
                float a  = rm[((size_t)bm * 2 + 0) * NHW + gy * NW + gx];
                float bb = rm[((size_t)bm * 2 + 1) * NHW + gy * NW + gx];
                v = fmaxf(1.0f / (1.0f + expf(-a)), 1.0f / (1.0f + expf(-bb)));
            }
            cs[ly][lx] = v;
        }
    }
    __syncthreads();

    if (t < 64) {
        float s = 0.0f;
#pragma unroll
        for (int ky = 0; ky < 5; ky++)
#pragma unroll
            for (int kx = 0; kx < 5; kx++)
                s += cs[ky][t + kx] * g[ky * 5 + kx];
        smask[t] = (s > THRE) ? 1.0f : 0.0f;
    }
    __syncthreads();

    // comm counter: image-0 blocks only; wave 0 reduces the 64 mask values
    if (m == 0 && t < 64) {
        float cnt = smask[t];
#pragma unroll
        for (int off = 32; off; off >>= 1) cnt += __shfl_down(cnt, off, 64);
        if (t == 0 && cnt != 0.0f) atomicAdd(counter, cnt);
    }

    // ---- convert + LDS transpose (both subtiles) ----
#pragma unroll
    for (int k = 0; k < 4; k++) {
#pragma unroll
        for (int j = 0; j < 4; j++) {
            const float mA = (m == 0) ? 1.0f : smask[u * 4 + j];
            const float mB = (m == 0) ? 1.0f : smask[32 + u * 4 + j];
            __half2 hA = __halves2half2(__float2half(fA[2 * k][j] * mA),
                                        __float2half(fA[2 * k + 1][j] * mA));
            __half2 hB = __halves2half2(__float2half(fB[2 * k][j] * mB),
                                        __float2half(fB[2 * k + 1][j] * mB));
            tileA[(u * 4 + j) * WPAD + cp + 32 * k] = *reinterpret_cast<unsigned int*>(&hA);
            tileB[(u * 4 + j) * WPAD + cp + 32 * k] = *reinterpret_cast<unsigned int*>(&hB);
        }
    }
    __syncthreads();

    // ---- stores: 1 KB contiguous per wave per iter ----
    const int uu = t & 31;      // 32 channel-octets
    const int pw = t >> 5;      // 0..7
#pragma unroll
    for (int j2 = 0; j2 < 4; j2++) {
        const int pl = pw + j2 * 8;
        const unsigned int* srcA = tileA + pl * WPAD + uu * 4;
        const unsigned int* srcB = tileB + pl * WPAD + uu * 4;
        uint4 valA = make_uint4(srcA[0], srcA[1], srcA[2], srcA[3]);
        uint4 valB = make_uint4(srcB[0], srcB[1], srcB[2], srcB[3]);
        *reinterpret_cast<uint4*>(xt + ((size_t)bm * NHW + p0 + pl) * NC + uu * 8) = valA;
        *reinterpret_cast<uint4*>(xt + ((size_t)bm * NHW + p0 + 32 + pl) * NC + uu * 8) = valB;
    }
}

// ---------------- fused v6: affine taps + comm_rate write folded in ---------
// block: 32 consecutive pixels (one image row), 256 thr = 4 waves.
// Each wave: 4 j-iters x 2 pixels (half-wave per pixel). lane&31 owns 8 ch.
// Rolling (pixel-pair, m) prefetch; sx/sy affine in pl (precomputed per block).
__global__ __launch_bounds__(256) void fused_kernel(const __half* __restrict__ xt,
                                                    const float* __restrict__ M,
                                                    const float* __restrict__ counter,
                                                    float* __restrict__ out) {
    const int tid = threadIdx.x, wid = tid >> 6, lane = tid & 63;
    const int half = lane >> 5, cl = lane & 31;
    const int nblk = NB * (NHW / 32);          // 2304, divisible by 8
    const int bid = (int)((blockIdx.x & 7) * (nblk / 8) + (blockIdx.x >> 3));
    const int b = bid / (NHW / 32);
    const int p0 = (bid % (NHW / 32)) * 32;

    // comm_rate scalar: counter complete (transpose finished in-stream)
    if (bid == 0 && tid == 0)
        out[(size_t)NB * NC * NHW] = *counter / (float)(NB * NHW);

    __shared__ float otile[32][260];
    __shared__ float sxAB[NL][4];   // {sxA, sxB, syA, syB} per m

    const int h = p0 / NW;
    const int w0 = p0 - h * NW;

    if (tid < NL) {
        const int m = tid;
        const float* Mb = M + ((size_t)(b * NL) * NL + m) * 16;
        const float gy = (h + 0.5f) * (2.0f / NH) - 1.0f;
        float th0 = Mb[0];
        float th1 = Mb[1] * ((float)NH / (float)NW);
        float th2 = Mb[3] * (2.0f / (0.4f * (float)NW));
        float th3 = Mb[4] * ((float)NW / (float)NH);
        float th4 = Mb[5];
        float th5 = Mb[7] * (2.0f / (0.4f * (float)NH));
        // gx(pl) = (w0+pl+0.5)*(2/NW) - 1  ->  sx(pl) = sxA*pl + sxB
        const float gxA = 2.0f / NW;
        const float gxB = (w0 + 0.5f) * (2.0f / NW) - 1.0f;
        float pxnA = th0 * gxA;
        float pxnB = th0 * gxB + th1 * gy + th2;
        float pynA = th3 * gxA;
        float pynB = th3 * gxB + th4 * gy + th5;
        sxAB[m][0] = pxnA * (float)NW * 0.5f;
        sxAB[m][1] = ((pxnB + 1.0f) * (float)NW - 1.0f) * 0.5f;
        sxAB[m][2] = pynA * (float)NH * 0.5f;
        sxAB[m][3] = ((pynB + 1.0f) * (float)NH - 1.0f) * 0.5f;
    }
    __syncthreads();

    float wtb[2][4];
    uint4 raw[2][4];

    auto issue = [&](int jj, int mm, int bk) {
        const float plf = (float)(wid * 8 + jj * 2 + half);
        float sx = sxAB[mm][0] * plf + sxAB[mm][1];
        float sy = sxAB[mm][2] * plf + sxAB[mm][3];
        float x0 = floorf(sx), y0 = floorf(sy);
        float fx = sx - x0, fy = sy - y0;
        const __half* base = xt + (size_t)(b * NL + mm) * NHW * NC + cl * 8;
#pragma unroll
        for (int ty = 0; ty < 2; ty++) {
#pragma unroll
            for (int tx = 0; tx < 2; tx++) {
                int tt = ty * 2 + tx;
                float xf = x0 + (float)tx, yf = y0 + (float)ty;
                bool valid = (xf >= 0.0f) && (xf <= (float)(NW - 1)) &&
                             (yf >= 0.0f) && (yf <= (float)(NH - 1));
                int ix = (int)fminf(fmaxf(xf, 0.0f), (float)(NW - 1));
                int iy = (int)fminf(fmaxf(yf, 0.0f), (float)(NH - 1));
                float wx = tx ? fx : (1.0f - fx);
                float wy = ty ? fy : (1.0f - fy);
                wtb[bk][tt] = wx * wy * (valid ? 1.0f : 0.0f);
                raw[bk][tt] = *reinterpret_cast<const uint4*>(
                    base + (size_t)(iy * NW + ix) * NC);
            }
        }
    };

    issue(0, 0, 0);

#pragma unroll
    for (int j = 0; j < 4; j++) {
        const int pl = wid * 8 + j * 2 + half;

        float v[NL][8];
        float dt[NL];

#pragma unroll
        for (int m = 0; m < NL; m++) {
            const int cnt = j * 5 + m;
            const int bk = cnt & 1;
            if (cnt + 1 < 20) issue((cnt + 1) / 5, (cnt + 1) % 5, (cnt + 1) & 1);

            float acc[8] = {0.f, 0.f, 0.f, 0.f, 0.f, 0.f, 0.f, 0.f};
#pragma unroll
            for (int tt = 0; tt < 4; tt++) {
                const __half2* h2 = reinterpret_cast<const __half2*>(&raw[bk][tt]);
                const float wv = wtb[bk][tt];
#pragma unroll
                for (int q = 0; q < 4; q++) {
                    float2 ff = __half22float2(h2[q]);
                    acc[2 * q]     += wv * ff.x;
                    acc[2 * q + 1] += wv * ff.y;
                }
            }
            float d = 0.f;
#pragma unroll
            for (int k = 0; k < 8; k++) { v[m][k] = acc[k]; d += v[0][k] * acc[k]; }
            dt[m] = d;
        }

#pragma unroll
        for (int m = 0; m < NL; m++) {
#pragma unroll
            for (int msk = 1; msk < 32; msk <<= 1)
                dt[m] += __shfl_xor(dt[m], msk, 64);
        }

        float mx = dt[0] * (1.0f / 16.0f);
#pragma unroll
        for (int m = 1; m < NL; m++) mx = fmaxf(mx, dt[m] * (1.0f / 16.0f));
        float pw[NL], sum = 0.0f;
#pragma unroll
        for (int m = 0; m < NL; m++) {
            pw[m] = __expf(dt[m] * (1.0f / 16.0f) - mx);
            sum += pw[m];
        }
        float inv = 1.0f / sum;

#pragma unroll
        for (int k = 0; k < 8; k++) {
            float o = 0.0f;
#pragma unroll
            for (int m = 0; m < NL; m++) o += pw[m] * v[m][k];
            otile[pl][cl * 8 + k] = o * inv;
        }
    }
    __syncthreads();

    const int u = tid & 7;
#pragma unroll
    for (int k = 0; k < 8; k++) {
        const int c = (tid >> 3) + k * 32;
        float4 val = make_float4(otile[u * 4 + 0][c], otile[u * 4 + 1][c],
                                 otile[u * 4 + 2][c], otile[u * 4 + 3][c]);
        *reinterpret_cast<float4*>(out + ((size_t)b * NC + c) * NHW + p0 + u * 4) = val;
    }
}

extern "C" void kernel_launch(void* const* d_in, const int* in_sizes, int n_in,
                              void* d_out, int out_size, void* d_ws, size_t ws_size,
                              hipStream_t stream) {
    const float* x  = (const float*)d_in[0];
    const float* rm = (const float*)d_in[1];
    const float* M  = (const float*)d_in[2];
    const float* g  = (const float*)d_in[3];
    float* out = (float*)d_out;

    float* counter = (float*)d_ws;                        // 16 floats (pad)
    __half* xt     = (__half*)(counter + 16);             // 20*NHW*NC halves

    hipMemsetAsync(counter, 0, sizeof(float), stream);

    transpose_kernel<<<NB * NL * (NHW / 64), 256, 0, stream>>>(x, rm, g, xt, counter);
    fused_kernel<<<NB * (NHW / 32), 256, 0, stream>>>(xt, M, counter, out);
}